// Round 11
// baseline (423.683 us; speedup 1.0000x reference)
//
#include <hip/hip_runtime.h>

// LDS row pitch in ushorts: 136*2=272B -> dword stride 68 -> bank step 4 ->
// only 2-way aliasing (free). 272 is a multiple of 16 -> rows stay 16B-aligned.
#define P 136

typedef __attribute__((ext_vector_type(8))) short short8;
typedef __attribute__((ext_vector_type(4))) float f32x4;

__device__ __forceinline__ unsigned short f2bf(float f) {
  union { float f; unsigned u; } v; v.f = f;
  unsigned u = v.u + 0x7fffu + ((v.u >> 16) & 1u);   // RNE
  return (unsigned short)(u >> 16);
}
__device__ __forceinline__ float bf2f(unsigned short h) {
  union { unsigned u; float f; } v; v.u = ((unsigned)h) << 16;
  return v.f;
}
// pack two floats -> bf16x2 dword in 3 VALU ops:
// round-half-away (u+0x8000, trunc hi16) + v_perm_b32 merge.
// vs RNE: differs only at exact ties (+0.5 ulp bias there) — invisible at bf16.
// R9 lesson: the inline-asm v_cvt_pk_bf16_f32 single-op version produced NaN
// bit patterns on gfx950 (semantics mismatch) — this 3-op form is proven.
__device__ __forceinline__ unsigned pack2bf(float x, float y) {
  union { float f; unsigned u; } a, b; a.f = x; b.f = y;
  return __builtin_amdgcn_perm(b.u + 0x8000u, a.u + 0x8000u, 0x07060302u);
}
// silu via hw approx rcp (rel err ~1e-7 << bf16 rounding).
__device__ __forceinline__ float silu_f(float x) {
  float e = __expf(-x);
  return x * __builtin_amdgcn_rcpf(1.0f + e);
}

// Transposed-GEMM building blocks. D[m=feat][n=row]:
//   A = W^T [feat][k] in REGISTERS (8 x short8 per wave, rows m0w..m0w+31)
//   B = X   [row][k]  in LDS, pitch P (contiguous b128 reads)
// C/D: lane holds n(row)=l16 (per ct tile), m(feat)=m0w+rt*16+q*4+r -> 4
// consecutive feature cols per lane => packed 8B epilogue stores.
__device__ __forceinline__ void load_A128(const unsigned short* __restrict__ W,
                                          int m0w, int l16, int q, short8 a[2][4]) {
#pragma unroll
  for (int rt = 0; rt < 2; ++rt)
#pragma unroll
    for (int kt = 0; kt < 4; ++kt)
      a[rt][kt] = *(const short8*)&W[(m0w + rt * 16 + l16) * 128 + kt * 32 + q * 8];
}

// full 4-K-tile GEMM, accumulator initialized with (c0i, c1i) at kt==0
template <int CT>
__device__ __forceinline__ void gemm_T_init(const short8 a[2][4],
                                            const unsigned short* sB,
                                            int l16, int q, f32x4 acc[2][CT],
                                            f32x4 c0i, f32x4 c1i) {
#pragma unroll
  for (int kt = 0; kt < 4; ++kt)
#pragma unroll
    for (int ct = 0; ct < CT; ++ct) {
      short8 b = *(const short8*)&sB[(ct * 16 + l16) * P + kt * 32 + q * 8];
      f32x4 c0 = (kt == 0) ? c0i : acc[0][ct];
      f32x4 c1 = (kt == 0) ? c1i : acc[1][ct];
      acc[0][ct] = __builtin_amdgcn_mfma_f32_16x16x32_bf16(a[0][kt], b, c0, 0, 0, 0);
      acc[1][ct] = __builtin_amdgcn_mfma_f32_16x16x32_bf16(a[1][kt], b, c1, 0, 0, 0);
    }
}

// accumulate-into-existing variant
template <int CT>
__device__ __forceinline__ void gemm_T_acc(const short8 a[2][4],
                                           const unsigned short* sB,
                                           int l16, int q, f32x4 acc[2][CT]) {
#pragma unroll
  for (int kt = 0; kt < 4; ++kt)
#pragma unroll
    for (int ct = 0; ct < CT; ++ct) {
      short8 b = *(const short8*)&sB[(ct * 16 + l16) * P + kt * 32 + q * 8];
      acc[0][ct] = __builtin_amdgcn_mfma_f32_16x16x32_bf16(a[0][kt], b, acc[0][ct], 0, 0, 0);
      acc[1][ct] = __builtin_amdgcn_mfma_f32_16x16x32_bf16(a[1][kt], b, acc[1][ct], 0, 0, 0);
    }
}

// epilogue with bias-add from LDS (R5-proven form — keeps bias out of long
// live ranges; edge_kernel sits exactly at the 128-reg/4-wave boundary)
template <bool SILU, int CT>
__device__ __forceinline__ void epilogue_T(const f32x4 acc[2][CT], const float* bias,
                                           unsigned short* sOut, int m0w, int l16,
                                           int q) {
#pragma unroll
  for (int rt = 0; rt < 2; ++rt) {
    int f0 = m0w + rt * 16 + q * 4;
    float4 bv = *(const float4*)&bias[f0];   // bias arrays are __align__(16)
#pragma unroll
    for (int ct = 0; ct < CT; ++ct) {
      float v0 = acc[rt][ct][0] + bv.x, v1 = acc[rt][ct][1] + bv.y;
      float v2 = acc[rt][ct][2] + bv.z, v3 = acc[rt][ct][3] + bv.w;
      if (SILU) { v0 = silu_f(v0); v1 = silu_f(v1); v2 = silu_f(v2); v3 = silu_f(v3); }
      uint2 w; w.x = pack2bf(v0, v1); w.y = pack2bf(v2, v3);
      *(uint2*)&sOut[(ct * 16 + l16) * P + f0] = w;
    }
  }
}

// epilogue without bias-add (bias folded into MFMA C-init; node/grid only)
template <bool SILU, int CT>
__device__ __forceinline__ void epilogue_nb(const f32x4 acc[2][CT],
                                            unsigned short* sOut, int m0w, int l16,
                                            int q) {
#pragma unroll
  for (int rt = 0; rt < 2; ++rt) {
    int f0 = m0w + rt * 16 + q * 4;
#pragma unroll
    for (int ct = 0; ct < CT; ++ct) {
      float v0 = acc[rt][ct][0], v1 = acc[rt][ct][1];
      float v2 = acc[rt][ct][2], v3 = acc[rt][ct][3];
      if (SILU) { v0 = silu_f(v0); v1 = silu_f(v1); v2 = silu_f(v2); v3 = silu_f(v3); }
      uint2 w; w.x = pack2bf(v0, v1); w.y = pack2bf(v2, v3);
      *(uint2*)&sOut[(ct * 16 + l16) * P + f0] = w;
    }
  }
}

// ---------------------------------------------------------------------------
// Merged fold + hist kernel (256 threads):
//   blocks [0,64):  weight folding, b = blk*2 + (tid>>7), t = tid&127
//                   (nw2/ew2 rows read as float4 — 4x fewer load issues)
//   blocks [64,..): histogram of tgt, 16 edges/thread (ILP over atomic latency)
// ---------------------------------------------------------------------------
__global__ __launch_bounds__(256) void fold_hist_kernel(
    const float* __restrict__ nw1, const float* __restrict__ nw2,
    const float* __restrict__ nb2, const float* __restrict__ ew2,
    const float* __restrict__ eb2, const float* __restrict__ mw1,
    const float* __restrict__ mb1, const float* __restrict__ mw2,
    const float* __restrict__ uw1, const float* __restrict__ uw2,
    const float* __restrict__ ew1,
    unsigned short* __restrict__ nw1t, unsigned short* __restrict__ wnt,
    unsigned short* __restrict__ wct, unsigned short* __restrict__ mw2t,
    unsigned short* __restrict__ uw1t, unsigned short* __restrict__ uw2t,
    unsigned short* __restrict__ ew1t8,
    float* __restrict__ bn, float* __restrict__ bc,
    const int* __restrict__ eidx, int* __restrict__ hist, int E) {
  if (blockIdx.x >= 64) {
    int e0 = (blockIdx.x - 64) * 4096 + threadIdx.x * 16;
    if (e0 + 15 < E && (E & 3) == 0) {
      int4 t0 = *(const int4*)&eidx[E + e0];
      int4 t1 = *(const int4*)&eidx[E + e0 + 4];
      int4 t2 = *(const int4*)&eidx[E + e0 + 8];
      int4 t3 = *(const int4*)&eidx[E + e0 + 12];
      atomicAdd(&hist[t0.x], 1); atomicAdd(&hist[t0.y], 1);
      atomicAdd(&hist[t0.z], 1); atomicAdd(&hist[t0.w], 1);
      atomicAdd(&hist[t1.x], 1); atomicAdd(&hist[t1.y], 1);
      atomicAdd(&hist[t1.z], 1); atomicAdd(&hist[t1.w], 1);
      atomicAdd(&hist[t2.x], 1); atomicAdd(&hist[t2.y], 1);
      atomicAdd(&hist[t2.z], 1); atomicAdd(&hist[t2.w], 1);
      atomicAdd(&hist[t3.x], 1); atomicAdd(&hist[t3.y], 1);
      atomicAdd(&hist[t3.z], 1); atomicAdd(&hist[t3.w], 1);
    } else {
#pragma unroll
      for (int k = 0; k < 16; ++k) {
        int e = e0 + k;
        if (e < E) atomicAdd(&hist[eidx[E + e]], 1);
      }
    }
    return;
  }
  int b = blockIdx.x * 2 + (threadIdx.x >> 7);  // output col
  int t = threadIdx.x & 127;                    // input row
  const float4* nr = (const float4*)&nw2[t * 128];
  const float4* er = (const float4*)&ew2[t * 128];
  float accn = 0.f, accc = 0.f;
  for (int j4 = 0; j4 < 32; ++j4) {
    float4 a = nr[j4];
    float4 e = er[j4];
    int j = j4 * 4;
    accn += a.x * mw1[j * 128 + b]       + a.y * mw1[(j + 1) * 128 + b] +
            a.z * mw1[(j + 2) * 128 + b] + a.w * mw1[(j + 3) * 128 + b];
    accc += e.x * mw1[(128 + j) * 128 + b]     + e.y * mw1[(129 + j) * 128 + b] +
            e.z * mw1[(130 + j) * 128 + b]     + e.w * mw1[(131 + j) * 128 + b];
  }
  wnt[b * 128 + t] = f2bf(accn);
  wct[b * 128 + t] = f2bf(accc);
  nw1t[b * 128 + t] = f2bf(nw1[t * 128 + b]);
  mw2t[b * 128 + t] = f2bf(mw2[t * 128 + b]);
  uw1t[b * 128 + t] = f2bf(uw1[t * 128 + b]);
  uw2t[b * 128 + t] = f2bf(uw2[t * 128 + b]);
  if (t < 8) ew1t8[b * 8 + t] = (t < 6) ? f2bf(ew1[t * 128 + b]) : (unsigned short)0;
  if (b == 0) {
    float sn = 0.f, sc = 0.f;
    for (int j = 0; j < 128; ++j) {
      sn += nb2[j] * mw1[j * 128 + t];
      sc += eb2[j] * mw1[(128 + j) * 128 + t];
    }
    bn[t] = sn;
    bc[t] = mb1[t] + sc;
  }
}

// Wave-shuffle scan: 2 barriers instead of 20 (Hillis-Steele over LDS).
__global__ __launch_bounds__(1024) void scan_kernel(const int* __restrict__ hist,
                                                    int* __restrict__ cursor, int G) {
  __shared__ int wsum[16];
  int tid = threadIdx.x;
  int lane = tid & 63, wv = tid >> 6;
  int per = (G + 1023) >> 10;
  int b0 = tid * per;
  bool vec = ((per & 3) == 0) && ((G & 3) == 0) && (b0 + per <= G);
  int sum = 0;
  if (vec) {
    for (int i = 0; i < per; i += 4) {
      int4 h = *(const int4*)&hist[b0 + i];
      sum += h.x + h.y + h.z + h.w;
    }
  } else {
    for (int i = 0; i < per; ++i)
      if (b0 + i < G) sum += hist[b0 + i];
  }
  // inclusive scan within wave
  int inc = sum;
#pragma unroll
  for (int off = 1; off < 64; off <<= 1) {
    int v = __shfl_up(inc, off, 64);
    if (lane >= off) inc += v;
  }
  if (lane == 63) wsum[wv] = inc;
  __syncthreads();
  if (wv == 0) {
    int v = (lane < 16) ? wsum[lane] : 0;
#pragma unroll
    for (int off = 1; off < 16; off <<= 1) {
      int t2 = __shfl_up(v, off, 64);
      if (lane >= off) v += t2;
    }
    if (lane < 16) wsum[lane] = v;
  }
  __syncthreads();
  int wpre = (wv == 0) ? 0 : wsum[wv - 1];
  int run = wpre + inc - sum;   // exclusive prefix for this thread's range
  if (vec) {
    for (int i = 0; i < per; i += 4) {
      int4 h = *(const int4*)&hist[b0 + i];
      int4 c;
      c.x = run;
      c.y = c.x + h.x;
      c.z = c.y + h.y;
      c.w = c.z + h.z;
      *(int4*)&cursor[b0 + i] = c;
      run = c.w + h.w;
    }
  } else {
    for (int i = 0; i < per; ++i)
      if (b0 + i < G) {
        cursor[b0 + i] = run;
        run += hist[b0 + i];
      }
  }
}

// ---------------------------------------------------------------------------
// Merged node + scatter kernel (256 threads):
//   blocks [0,nNode):   node MLP: node_pre = silu(x@nw1+nb1) @ Wn + bn
//   blocks [nNode,..):  scatter (src,tgt) into sorted position, 16 edges/thread
// Scatter stores are nontemporal: random 8B stores write-allocate a 64B L2
// line each (8x amplification, R2: WRITE 90MB for 34MB useful); nt hint
// bypasses allocate. Kernel-boundary coherence keeps edge_kernel reads safe.
// ---------------------------------------------------------------------------
__global__ __launch_bounds__(256, 3) void scatter_node_kernel(
    const int* __restrict__ eidx, int* __restrict__ cursor,
    int2* __restrict__ st, int E, int nNode,
    const float* __restrict__ x, const float* __restrict__ nb1,
    const unsigned short* __restrict__ nw1t, const unsigned short* __restrict__ wnt,
    const float* __restrict__ bn, unsigned short* __restrict__ node_pre, int N) {
  __shared__ __align__(16) unsigned short s_x[128 * P];
  __shared__ __align__(16) float s_b1[128];
  __shared__ __align__(16) float s_bn[128];

  if (blockIdx.x >= (unsigned)nNode) {
    int e0 = (blockIdx.x - nNode) * 4096 + threadIdx.x * 16;
    long long* stq = (long long*)st;
    if (e0 + 15 < E && (E & 3) == 0) {
      int4 sv[4], tv[4];
#pragma unroll
      for (int g = 0; g < 4; ++g) {
        sv[g] = *(const int4*)&eidx[e0 + g * 4];
        tv[g] = *(const int4*)&eidx[E + e0 + g * 4];
      }
      int pos[16];
#pragma unroll
      for (int g = 0; g < 4; ++g) {
        pos[g * 4 + 0] = atomicAdd(&cursor[tv[g].x], 1);
        pos[g * 4 + 1] = atomicAdd(&cursor[tv[g].y], 1);
        pos[g * 4 + 2] = atomicAdd(&cursor[tv[g].z], 1);
        pos[g * 4 + 3] = atomicAdd(&cursor[tv[g].w], 1);
      }
#pragma unroll
      for (int g = 0; g < 4; ++g) {
        __builtin_nontemporal_store(
            (long long)(unsigned)sv[g].x | ((long long)tv[g].x << 32), &stq[pos[g * 4 + 0]]);
        __builtin_nontemporal_store(
            (long long)(unsigned)sv[g].y | ((long long)tv[g].y << 32), &stq[pos[g * 4 + 1]]);
        __builtin_nontemporal_store(
            (long long)(unsigned)sv[g].z | ((long long)tv[g].z << 32), &stq[pos[g * 4 + 2]]);
        __builtin_nontemporal_store(
            (long long)(unsigned)sv[g].w | ((long long)tv[g].w << 32), &stq[pos[g * 4 + 3]]);
      }
    } else {
#pragma unroll
      for (int k = 0; k < 16; ++k) {
        int e = e0 + k;
        if (e < E) {
          int sg = eidx[e];
          int tg = eidx[E + e];
          int p = atomicAdd(&cursor[tg], 1);
          __builtin_nontemporal_store(
              (long long)(unsigned)sg | ((long long)tg << 32), &stq[p]);
        }
      }
    }
    return;
  }

  int tid = threadIdx.x;
  long base = (long)blockIdx.x * 128;

#pragma unroll
  for (int i = 0; i < 16; ++i) {
    int flat = tid + i * 256;      // 4096 float4 = 128 rows x 32
    int row = flat >> 5;
    int c4 = (flat & 31) << 2;
    float4 v = make_float4(0.f, 0.f, 0.f, 0.f);
    if (base + row < N) v = *(const float4*)&x[(base + row) * 128 + c4];
    uint2 w; w.x = pack2bf(v.x, v.y); w.y = pack2bf(v.z, v.w);
    *(uint2*)&s_x[row * P + c4] = w;
  }
  if (tid < 128) { s_b1[tid] = nb1[tid]; s_bn[tid] = bn[tid]; }
  __syncthreads();

  int wave = tid >> 6, lane = tid & 63;
  int q = lane >> 4, l16 = lane & 15;
  int m0w = wave * 32;

  f32x4 b1_0 = *(const f32x4*)&s_b1[m0w + q * 4];
  f32x4 b1_1 = *(const f32x4*)&s_b1[m0w + 16 + q * 4];

  short8 a1[2][4];
  load_A128(nw1t, m0w, l16, q, a1);
  f32x4 acc[2][8];
  gemm_T_init<8>(a1, s_x, l16, q, acc, b1_0, b1_1);
  __syncthreads();
  epilogue_nb<true, 8>(acc, s_x, m0w, l16, q);
  __syncthreads();

  f32x4 bn_0 = *(const f32x4*)&s_bn[m0w + q * 4];
  f32x4 bn_1 = *(const f32x4*)&s_bn[m0w + 16 + q * 4];
  short8 a2[2][4];
  load_A128(wnt, m0w, l16, q, a2);
  gemm_T_init<8>(a2, s_x, l16, q, acc, bn_0, bn_1);

  // store node_pre[node][feat] packed 8B (bias already folded)
#pragma unroll
  for (int rt = 0; rt < 2; ++rt) {
    int f0 = m0w + rt * 16 + q * 4;
#pragma unroll
    for (int ct = 0; ct < 8; ++ct) {
      long n = base + ct * 16 + l16;
      if (n < N) {
        uint2 w;
        w.x = pack2bf(acc[rt][ct][0], acc[rt][ct][1]);
        w.y = pack2bf(acc[rt][ct][2], acc[rt][ct][3]);
        *(uint2*)&node_pre[n * 128 + f0] = w;
      }
    }
  }
}

// ---------------------------------------------------------------------------
// Edge kernel — R5 structure (proven; VALUBusy 71%, occ 41%, 4 blocks/CU).
// R7 lesson: bias-fold into MFMA C-init crossed the 128-reg boundary (-12us).
// R6 lesson: finer reduction granularity tripled atomic WRITE_SIZE.
// R11: (a) s_setprio(1) around MFMA clusters — edge blocks are independent
// (phase-diverse residents), the regime where setprio paid on attn (m191);
// (b) reduction processes 2 rows/iter (16 iters), SAME colpair flush
// granularity and atomic count as R5.
// ---------------------------------------------------------------------------
__global__ __launch_bounds__(256, 3) void edge_kernel(
    const int2* __restrict__ st_sorted, const float* __restrict__ node_pos,
    const float* __restrict__ grid_pos, const float* __restrict__ ori,
    const unsigned short* __restrict__ ew1t8, const float* __restrict__ eb1,
    const unsigned short* __restrict__ wct, const float* __restrict__ bc,
    const unsigned short* __restrict__ node_pre, float* __restrict__ sums, int E) {
  __shared__ __align__(16) unsigned short s_h[128 * P];
  __shared__ int s_src[128];
  __shared__ int s_tgt[128];
  __shared__ __align__(16) float s_eb1[128];
  __shared__ __align__(16) float s_bc[128];

  int tid = threadIdx.x;
  int base = blockIdx.x * 128;

  if (tid < 128) {
    s_eb1[tid] = eb1[tid];
    s_bc[tid] = bc[tid];
    int eg = base + tid;
    int s = 0, tg = -1;
    float a0 = 0.f, a1 = 0.f, a2 = 0.f, a3 = 0.f, a4 = 0.f, a5 = 0.f;
    if (eg < E) {
      int2 st = st_sorted[eg];
      s = st.x; tg = st.y;
      // vectorized gathers (dwordx4 needs only dword alignment on CDNA)
      float2 p01 = *(const float2*)&node_pos[s * 3];
      float pz = node_pos[s * 3 + 2];
      float2 g01 = *(const float2*)&grid_pos[tg * 3];
      float gz = grid_pos[tg * 3 + 2];
      float4 o0 = *(const float4*)&ori[(long)s * 9];      // o[0..3]
      float4 o1 = *(const float4*)&ori[(long)s * 9 + 4];  // o[4..7]
      float o8 = ori[(long)s * 9 + 8];
      float rx = g01.x - p01.x, ry = g01.y - p01.y, rz = gz - pz;
      a0 = p01.x; a1 = p01.y; a2 = pz;
      a3 = rx * o0.x + ry * o0.w + rz * o1.z;   // o0,o3,o6
      a4 = rx * o0.y + ry * o1.x + rz * o1.w;   // o1,o4,o7
      a5 = rx * o0.z + ry * o1.y + rz * o8;     // o2,o5,o8
    }
    s_src[tid] = s;
    s_tgt[tid] = tg;
    uint4 w0;
    w0.x = pack2bf(a0, a1); w0.y = pack2bf(a2, a3); w0.z = pack2bf(a4, a5); w0.w = 0u;
    *(uint4*)&s_h[tid * P] = w0;   // attr row [edge][k0..7]
  }

  int wave = tid >> 6, lane = tid & 63;
  int q = lane >> 4, l16 = lane & 15;
  int m0w = wave * 32;
  short8 z8 = (short8){0, 0, 0, 0, 0, 0, 0, 0};
  const f32x4 Z = (f32x4){0.f, 0.f, 0.f, 0.f};

  // ew1^T rows (K=8) -> registers, q==0 lanes only (issued pre-barrier,
  // overlaps the geometry phase; L2-resident)
  short8 ae0 = z8, ae1 = z8;
  if (q == 0) {
    ae0 = *(const short8*)&ew1t8[(m0w + l16) * 8];
    ae1 = *(const short8*)&ew1t8[(m0w + 16 + l16) * 8];
  }

  __syncthreads();

  // --- node_pre prefetch: issue NOW, consume after the h1 epilogue. ---
  // All 64 lanes: lane (q,l16) of tile ct loads feats [m0w+q*8, m0w+q*8+8)
  // of row src[ct*16+l16] -> B[k=q*8+j][n=l16] with k spanning both rt tiles.
  short8 pre[8];
#pragma unroll
  for (int ct = 0; ct < 8; ++ct) {
    long srow = (long)s_src[ct * 16 + l16] * 128;
    pre[ct] = *(const short8*)&node_pre[srow + m0w + q * 8];
  }

  // GEMM0: D[h][edge] = ew1^T · attr^T (single K-tile, direct-init C=0)
  f32x4 acc[2][8];
  __builtin_amdgcn_s_setprio(1);
#pragma unroll
  for (int ct = 0; ct < 8; ++ct) {
    short8 b = z8;
    if (q == 0) b = *(const short8*)&s_h[(ct * 16 + l16) * P];
    acc[0][ct] = __builtin_amdgcn_mfma_f32_16x16x32_bf16(ae0, b, Z, 0, 0, 0);
    acc[1][ct] = __builtin_amdgcn_mfma_f32_16x16x32_bf16(ae1, b, Z, 0, 0, 0);
  }
  __builtin_amdgcn_s_setprio(0);
  __syncthreads();  // attr reads done before overwrite

  epilogue_T<true, 8>(acc, s_eb1, s_h, m0w, l16, q);   // h1 -> s_h[edge][feat]

  // Wc^T rows for this wave -> registers (L2-resident). Loaded here (not
  // earlier) so they don't add to VGPR pressure while acc is live for GEMM0.
  short8 awc[2][4];
  load_A128(wct, m0w, l16, q, awc);

  __syncthreads();

  // acc := node_pre[src[edge]][feat] from the prefetched fragments.
  // rt=0: A[i][k]=delta(k,i); rt=1: A[i][k]=delta(k,i+16).
  short8 aI_lo, aI_hi;
#pragma unroll
  for (int j = 0; j < 8; ++j) {
    aI_lo[j] = ((q * 8 + j) == l16) ? (short)0x3F80 : (short)0;
    aI_hi[j] = ((q * 8 + j) == (l16 + 16)) ? (short)0x3F80 : (short)0;
  }
  __builtin_amdgcn_s_setprio(1);
#pragma unroll
  for (int ct = 0; ct < 8; ++ct) {
    acc[0][ct] = __builtin_amdgcn_mfma_f32_16x16x32_bf16(aI_lo, pre[ct], Z, 0, 0, 0);
    acc[1][ct] = __builtin_amdgcn_mfma_f32_16x16x32_bf16(aI_hi, pre[ct], Z, 0, 0, 0);
  }

  // GEMM1: acc += Wc^T · h1^T
  gemm_T_acc<8>(awc, s_h, l16, q, acc);
  __builtin_amdgcn_s_setprio(0);
  __syncthreads();  // h1 reads done

  epilogue_T<true, 8>(acc, s_bc, s_h, m0w, l16, q);    // h2 -> s_h[edge][feat]
  __syncthreads();

  // segmented reduction: thread = (colpair, 32-row chunk); flush per run.
  // 2 rows/iter (16 iters) — SAME flush granularity/atomic count as R5.
  {
    int cp = tid & 63;
    int chunk = tid >> 6;       // 4 chunks x 32 rows
    int c0 = cp * 2;
    int row0 = chunk * 32;
    float v0 = 0.f, v1 = 0.f;
    int cur = s_tgt[row0];
    for (int rr = 0; rr < 16; ++rr) {
      int row = row0 + rr * 2;
      int tg0 = s_tgt[row];
      int tg1 = s_tgt[row + 1];
      unsigned w0 = *(const unsigned*)&s_h[row * P + c0];
      unsigned w1 = *(const unsigned*)&s_h[(row + 1) * P + c0];
      if (tg0 != cur) {
        if (cur >= 0) {
          atomicAdd(&sums[(long)cur * 128 + c0], v0);
          atomicAdd(&sums[(long)cur * 128 + c0 + 1], v1);
        }
        v0 = 0.f; v1 = 0.f; cur = tg0;
      }
      v0 += bf2f((unsigned short)w0);
      v1 += bf2f((unsigned short)(w0 >> 16));
      if (tg1 != cur) {
        if (cur >= 0) {
          atomicAdd(&sums[(long)cur * 128 + c0], v0);
          atomicAdd(&sums[(long)cur * 128 + c0 + 1], v1);
        }
        v0 = 0.f; v1 = 0.f; cur = tg1;
      }
      v0 += bf2f((unsigned short)w1);
      v1 += bf2f((unsigned short)(w1 >> 16));
    }
    if (cur >= 0) {
      atomicAdd(&sums[(long)cur * 128 + c0], v0);
      atomicAdd(&sums[(long)cur * 128 + c0 + 1], v1);
    }
  }
}

// ---------------------------------------------------------------------------
// Grid kernel (transposed): x = sums/clip(hist,1); y = x@mw2+mb2;
// out = silu(y@uw1+ub1)@uw2 + ub2.  Final store: packed float4.
// Tile = 32 grid rows (2 ct tiles) -> 1024 blocks = 4 blocks/CU. LDS ~19 KB.
// Bias folded into MFMA C-init throughout.
// ---------------------------------------------------------------------------
__global__ __launch_bounds__(256, 3) void grid_kernel(
    const float* __restrict__ sums, const int* __restrict__ hist,
    const float* __restrict__ mb2, const float* __restrict__ ub1,
    const float* __restrict__ ub2, const unsigned short* __restrict__ mw2t,
    const unsigned short* __restrict__ uw1t, const unsigned short* __restrict__ uw2t,
    float* __restrict__ out, int G) {
  __shared__ __align__(16) unsigned short s_x[32 * P];
  __shared__ __align__(16) float s_bm[128];
  __shared__ __align__(16) float s_b1[128];
  __shared__ __align__(16) float s_b2[128];
  int tid = threadIdx.x;
  long base = (long)blockIdx.x * 32;

#pragma unroll
  for (int i = 0; i < 4; ++i) {
    int flat = tid + i * 256;       // 1024 float4 = 32 rows x 32
    int row = flat >> 5;
    int c4 = (flat & 31) << 2;
    float4 v = make_float4(0.f, 0.f, 0.f, 0.f);
    float inv = 1.f;
    if (base + row < G) {
      v = *(const float4*)&sums[(base + row) * 128 + c4];
      int c = hist[base + row];
      inv = __builtin_amdgcn_rcpf((float)(c < 1 ? 1 : c));
    }
    uint2 w; w.x = pack2bf(v.x * inv, v.y * inv); w.y = pack2bf(v.z * inv, v.w * inv);
    *(uint2*)&s_x[row * P + c4] = w;
  }
  if (tid < 128) { s_bm[tid] = mb2[tid]; s_b1[tid] = ub1[tid]; s_b2[tid] = ub2[tid]; }
  __syncthreads();

  int wave = tid >> 6, lane = tid & 63;
  int q = lane >> 4, l16 = lane & 15;
  int m0w = wave * 32;

  f32x4 acc[2][2];
  short8 aw[2][4];

  f32x4 bm0 = *(const f32x4*)&s_bm[m0w + q * 4];
  f32x4 bm1 = *(const f32x4*)&s_bm[m0w + 16 + q * 4];
  f32x4 b10 = *(const f32x4*)&s_b1[m0w + q * 4];
  f32x4 b11 = *(const f32x4*)&s_b1[m0w + 16 + q * 4];
  f32x4 b20 = *(const f32x4*)&s_b2[m0w + q * 4];
  f32x4 b21 = *(const f32x4*)&s_b2[m0w + 16 + q * 4];

  // GEMM A: grid_feat = x@mw2 + mb2 (no activation)
  load_A128(mw2t, m0w, l16, q, aw);
  gemm_T_init<2>(aw, s_x, l16, q, acc, bm0, bm1);
  __syncthreads();
  epilogue_nb<false, 2>(acc, s_x, m0w, l16, q);
  __syncthreads();

  // GEMM B: silu(y@uw1 + ub1)
  load_A128(uw1t, m0w, l16, q, aw);
  gemm_T_init<2>(aw, s_x, l16, q, acc, b10, b11);
  __syncthreads();
  epilogue_nb<true, 2>(acc, s_x, m0w, l16, q);
  __syncthreads();

  // GEMM C: out = h@uw2 + ub2  (fp32 float4 stores, bias folded)
  load_A128(uw2t, m0w, l16, q, aw);
  gemm_T_init<2>(aw, s_x, l16, q, acc, b20, b21);

#pragma unroll
  for (int rt = 0; rt < 2; ++rt) {
    int f0 = m0w + rt * 16 + q * 4;
#pragma unroll
    for (int ct = 0; ct < 2; ++ct) {
      long g = base + ct * 16 + l16;
      if (g < G) {
        float4 o = make_float4(acc[rt][ct][0], acc[rt][ct][1],
                               acc[rt][ct][2], acc[rt][ct][3]);
        *(float4*)&out[g * 128 + f0] = o;
      }
    }
  }
}

extern "C" void kernel_launch(void* const* d_in, const int* in_sizes, int n_in,
                              void* d_out, int out_size, void* d_ws, size_t ws_size,
                              hipStream_t stream) {
  const float* x    = (const float*)d_in[0];
  const float* npos = (const float*)d_in[1];
  const float* gpos = (const float*)d_in[2];
  const int*   eidx = (const int*)d_in[3];
  const float* ori  = (const float*)d_in[4];
  const float* nw1 = (const float*)d_in[5];
  const float* nb1 = (const float*)d_in[6];
  const float* nw2 = (const float*)d_in[7];
  const float* nb2 = (const float*)d_in[8];
  const float* ew1 = (const float*)d_in[9];
  const float* eb1 = (const float*)d_in[10];
  const float* ew2 = (const float*)d_in[11];
  const float* eb2 = (const float*)d_in[12];
  const float* mw1 = (const float*)d_in[13];
  const float* mb1 = (const float*)d_in[14];
  const float* mw2 = (const float*)d_in[15];
  const float* mb2 = (const float*)d_in[16];
  const float* uw1 = (const float*)d_in[17];
  const float* ub1 = (const float*)d_in[18];
  const float* uw2 = (const float*)d_in[19];
  const float* ub2 = (const float*)d_in[20];

  int N = in_sizes[0] / 128;
  int G = in_sizes[2] / 3;
  int E = in_sizes[3] / 2;

  // ws layout within R1's proven footprint (~43 MB). Sorted-edge buffer
  // (E*8 = 8 MB) lives in d_out (16.8 MB) — dead until grid_kernel (last
  // launch); stream order makes the reuse safe.
  char* ws = (char*)d_ws;
  size_t off = 0;
  float* sums = (float*)(ws + off);            off += (size_t)G * 128 * 4;
  int* hist = (int*)(ws + off);                off += (size_t)G * 4;
  int* cursor = (int*)(ws + off);              off += (size_t)G * 4;
  unsigned short* node_pre = (unsigned short*)(ws + off); off += (size_t)N * 128 * 2;
  off = (off + 255) & ~(size_t)255;
  unsigned short* w_nw1t = (unsigned short*)(ws + off); off += 128 * 128 * 2;
  unsigned short* w_wnt  = (unsigned short*)(ws + off); off += 128 * 128 * 2;
  unsigned short* w_wct  = (unsigned short*)(ws + off); off += 128 * 128 * 2;
  unsigned short* w_mw2t = (unsigned short*)(ws + off); off += 128 * 128 * 2;
  unsigned short* w_uw1t = (unsigned short*)(ws + off); off += 128 * 128 * 2;
  unsigned short* w_uw2t = (unsigned short*)(ws + off); off += 128 * 128 * 2;
  unsigned short* w_ew1t8 = (unsigned short*)(ws + off); off += 128 * 8 * 2;
  float* bn = (float*)(ws + off); off += 128 * 4;
  float* bc = (float*)(ws + off); off += 128 * 4;

  int2* st_sorted = (int2*)d_out;   // scratch until grid_kernel overwrites it

  int nScat = (E + 4095) / 4096;    // 16 edges/thread
  int nNode = (N + 127) / 128;
  int nHist = (E + 4095) / 4096;    // 16 edges/thread

  // zero sums + hist (contiguous)
  hipMemsetAsync(sums, 0, ((size_t)G * 128 + G) * 4, stream);

  fold_hist_kernel<<<64 + nHist, 256, 0, stream>>>(
      nw1, nw2, nb2, ew2, eb2, mw1, mb1, mw2, uw1, uw2, ew1,
      w_nw1t, w_wnt, w_wct, w_mw2t, w_uw1t, w_uw2t, w_ew1t8, bn, bc,
      eidx, hist, E);
  scan_kernel<<<1, 1024, 0, stream>>>(hist, cursor, G);
  scatter_node_kernel<<<nNode + nScat, 256, 0, stream>>>(
      eidx, cursor, st_sorted, E, nNode,
      x, nb1, w_nw1t, w_wnt, bn, node_pre, N);
  edge_kernel<<<(E + 127) / 128, 256, 0, stream>>>(st_sorted, npos, gpos, ori,
                                                   w_ew1t8, eb1, w_wct, bc,
                                                   node_pre, sums, E);
  grid_kernel<<<(G + 31) / 32, 256, 0, stream>>>(sums, hist, mb2, ub1, ub2,
                                                 w_mw2t, w_uw1t, w_uw2t,
                                                 (float*)d_out, G);
}

// Round 12
// 388.187 us; speedup vs baseline: 1.0914x; 1.0914x over previous
//
#include <hip/hip_runtime.h>

// LDS row pitch in ushorts: 136*2=272B -> dword stride 68 -> bank step 4 ->
// only 2-way aliasing (free). 272 is a multiple of 16 -> rows stay 16B-aligned.
#define P 136

typedef __attribute__((ext_vector_type(8))) short short8;
typedef __attribute__((ext_vector_type(4))) float f32x4;

__device__ __forceinline__ unsigned short f2bf(float f) {
  union { float f; unsigned u; } v; v.f = f;
  unsigned u = v.u + 0x7fffu + ((v.u >> 16) & 1u);   // RNE
  return (unsigned short)(u >> 16);
}
__device__ __forceinline__ float bf2f(unsigned short h) {
  union { unsigned u; float f; } v; v.u = ((unsigned)h) << 16;
  return v.f;
}
// pack two floats -> bf16x2 dword in 3 VALU ops:
// round-half-away (u+0x8000, trunc hi16) + v_perm_b32 merge.
// vs RNE: differs only at exact ties (+0.5 ulp bias there) — invisible at bf16.
// R9 lesson: the inline-asm v_cvt_pk_bf16_f32 single-op version produced NaN
// bit patterns on gfx950 (semantics mismatch) — this 3-op form is proven.
__device__ __forceinline__ unsigned pack2bf(float x, float y) {
  union { float f; unsigned u; } a, b; a.f = x; b.f = y;
  return __builtin_amdgcn_perm(b.u + 0x8000u, a.u + 0x8000u, 0x07060302u);
}
// silu via hw approx rcp (rel err ~1e-7 << bf16 rounding).
__device__ __forceinline__ float silu_f(float x) {
  float e = __expf(-x);
  return x * __builtin_amdgcn_rcpf(1.0f + e);
}

// Transposed-GEMM building blocks. D[m=feat][n=row]:
//   A = W^T [feat][k] in REGISTERS (8 x short8 per wave, rows m0w..m0w+31)
//   B = X   [row][k]  in LDS, pitch P (contiguous b128 reads)
// C/D: lane holds n(row)=l16 (per ct tile), m(feat)=m0w+rt*16+q*4+r -> 4
// consecutive feature cols per lane => packed 8B epilogue stores.
__device__ __forceinline__ void load_A128(const unsigned short* __restrict__ W,
                                          int m0w, int l16, int q, short8 a[2][4]) {
#pragma unroll
  for (int rt = 0; rt < 2; ++rt)
#pragma unroll
    for (int kt = 0; kt < 4; ++kt)
      a[rt][kt] = *(const short8*)&W[(m0w + rt * 16 + l16) * 128 + kt * 32 + q * 8];
}

// full 4-K-tile GEMM, accumulator initialized with (c0i, c1i) at kt==0
template <int CT>
__device__ __forceinline__ void gemm_T_init(const short8 a[2][4],
                                            const unsigned short* sB,
                                            int l16, int q, f32x4 acc[2][CT],
                                            f32x4 c0i, f32x4 c1i) {
#pragma unroll
  for (int kt = 0; kt < 4; ++kt)
#pragma unroll
    for (int ct = 0; ct < CT; ++ct) {
      short8 b = *(const short8*)&sB[(ct * 16 + l16) * P + kt * 32 + q * 8];
      f32x4 c0 = (kt == 0) ? c0i : acc[0][ct];
      f32x4 c1 = (kt == 0) ? c1i : acc[1][ct];
      acc[0][ct] = __builtin_amdgcn_mfma_f32_16x16x32_bf16(a[0][kt], b, c0, 0, 0, 0);
      acc[1][ct] = __builtin_amdgcn_mfma_f32_16x16x32_bf16(a[1][kt], b, c1, 0, 0, 0);
    }
}

// accumulate-into-existing variant
template <int CT>
__device__ __forceinline__ void gemm_T_acc(const short8 a[2][4],
                                           const unsigned short* sB,
                                           int l16, int q, f32x4 acc[2][CT]) {
#pragma unroll
  for (int kt = 0; kt < 4; ++kt)
#pragma unroll
    for (int ct = 0; ct < CT; ++ct) {
      short8 b = *(const short8*)&sB[(ct * 16 + l16) * P + kt * 32 + q * 8];
      acc[0][ct] = __builtin_amdgcn_mfma_f32_16x16x32_bf16(a[0][kt], b, acc[0][ct], 0, 0, 0);
      acc[1][ct] = __builtin_amdgcn_mfma_f32_16x16x32_bf16(a[1][kt], b, acc[1][ct], 0, 0, 0);
    }
}

// epilogue with bias-add from LDS (R5-proven form — keeps bias out of long
// live ranges; edge_kernel sits exactly at the 128-reg/4-wave boundary)
template <bool SILU, int CT>
__device__ __forceinline__ void epilogue_T(const f32x4 acc[2][CT], const float* bias,
                                           unsigned short* sOut, int m0w, int l16,
                                           int q) {
#pragma unroll
  for (int rt = 0; rt < 2; ++rt) {
    int f0 = m0w + rt * 16 + q * 4;
    float4 bv = *(const float4*)&bias[f0];   // bias arrays are __align__(16)
#pragma unroll
    for (int ct = 0; ct < CT; ++ct) {
      float v0 = acc[rt][ct][0] + bv.x, v1 = acc[rt][ct][1] + bv.y;
      float v2 = acc[rt][ct][2] + bv.z, v3 = acc[rt][ct][3] + bv.w;
      if (SILU) { v0 = silu_f(v0); v1 = silu_f(v1); v2 = silu_f(v2); v3 = silu_f(v3); }
      uint2 w; w.x = pack2bf(v0, v1); w.y = pack2bf(v2, v3);
      *(uint2*)&sOut[(ct * 16 + l16) * P + f0] = w;
    }
  }
}

// epilogue without bias-add (bias folded into MFMA C-init; node/grid only)
template <bool SILU, int CT>
__device__ __forceinline__ void epilogue_nb(const f32x4 acc[2][CT],
                                            unsigned short* sOut, int m0w, int l16,
                                            int q) {
#pragma unroll
  for (int rt = 0; rt < 2; ++rt) {
    int f0 = m0w + rt * 16 + q * 4;
#pragma unroll
    for (int ct = 0; ct < CT; ++ct) {
      float v0 = acc[rt][ct][0], v1 = acc[rt][ct][1];
      float v2 = acc[rt][ct][2], v3 = acc[rt][ct][3];
      if (SILU) { v0 = silu_f(v0); v1 = silu_f(v1); v2 = silu_f(v2); v3 = silu_f(v3); }
      uint2 w; w.x = pack2bf(v0, v1); w.y = pack2bf(v2, v3);
      *(uint2*)&sOut[(ct * 16 + l16) * P + f0] = w;
    }
  }
}

// ---------------------------------------------------------------------------
// Merged fold + hist kernel (256 threads):
//   blocks [0,64):  weight folding, b = blk*2 + (tid>>7), t = tid&127
//                   (nw2/ew2 rows read as float4 — 4x fewer load issues)
//   blocks [64,..): histogram of tgt, 16 edges/thread (ILP over atomic latency)
// ---------------------------------------------------------------------------
__global__ __launch_bounds__(256) void fold_hist_kernel(
    const float* __restrict__ nw1, const float* __restrict__ nw2,
    const float* __restrict__ nb2, const float* __restrict__ ew2,
    const float* __restrict__ eb2, const float* __restrict__ mw1,
    const float* __restrict__ mb1, const float* __restrict__ mw2,
    const float* __restrict__ uw1, const float* __restrict__ uw2,
    const float* __restrict__ ew1,
    unsigned short* __restrict__ nw1t, unsigned short* __restrict__ wnt,
    unsigned short* __restrict__ wct, unsigned short* __restrict__ mw2t,
    unsigned short* __restrict__ uw1t, unsigned short* __restrict__ uw2t,
    unsigned short* __restrict__ ew1t8,
    float* __restrict__ bn, float* __restrict__ bc,
    const int* __restrict__ eidx, int* __restrict__ hist, int E) {
  if (blockIdx.x >= 64) {
    int e0 = (blockIdx.x - 64) * 4096 + threadIdx.x * 16;
    if (e0 + 15 < E && (E & 3) == 0) {
      int4 t0 = *(const int4*)&eidx[E + e0];
      int4 t1 = *(const int4*)&eidx[E + e0 + 4];
      int4 t2 = *(const int4*)&eidx[E + e0 + 8];
      int4 t3 = *(const int4*)&eidx[E + e0 + 12];
      atomicAdd(&hist[t0.x], 1); atomicAdd(&hist[t0.y], 1);
      atomicAdd(&hist[t0.z], 1); atomicAdd(&hist[t0.w], 1);
      atomicAdd(&hist[t1.x], 1); atomicAdd(&hist[t1.y], 1);
      atomicAdd(&hist[t1.z], 1); atomicAdd(&hist[t1.w], 1);
      atomicAdd(&hist[t2.x], 1); atomicAdd(&hist[t2.y], 1);
      atomicAdd(&hist[t2.z], 1); atomicAdd(&hist[t2.w], 1);
      atomicAdd(&hist[t3.x], 1); atomicAdd(&hist[t3.y], 1);
      atomicAdd(&hist[t3.z], 1); atomicAdd(&hist[t3.w], 1);
    } else {
#pragma unroll
      for (int k = 0; k < 16; ++k) {
        int e = e0 + k;
        if (e < E) atomicAdd(&hist[eidx[E + e]], 1);
      }
    }
    return;
  }
  int b = blockIdx.x * 2 + (threadIdx.x >> 7);  // output col
  int t = threadIdx.x & 127;                    // input row
  const float4* nr = (const float4*)&nw2[t * 128];
  const float4* er = (const float4*)&ew2[t * 128];
  float accn = 0.f, accc = 0.f;
  for (int j4 = 0; j4 < 32; ++j4) {
    float4 a = nr[j4];
    float4 e = er[j4];
    int j = j4 * 4;
    accn += a.x * mw1[j * 128 + b]       + a.y * mw1[(j + 1) * 128 + b] +
            a.z * mw1[(j + 2) * 128 + b] + a.w * mw1[(j + 3) * 128 + b];
    accc += e.x * mw1[(128 + j) * 128 + b]     + e.y * mw1[(129 + j) * 128 + b] +
            e.z * mw1[(130 + j) * 128 + b]     + e.w * mw1[(131 + j) * 128 + b];
  }
  wnt[b * 128 + t] = f2bf(accn);
  wct[b * 128 + t] = f2bf(accc);
  nw1t[b * 128 + t] = f2bf(nw1[t * 128 + b]);
  mw2t[b * 128 + t] = f2bf(mw2[t * 128 + b]);
  uw1t[b * 128 + t] = f2bf(uw1[t * 128 + b]);
  uw2t[b * 128 + t] = f2bf(uw2[t * 128 + b]);
  if (t < 8) ew1t8[b * 8 + t] = (t < 6) ? f2bf(ew1[t * 128 + b]) : (unsigned short)0;
  if (b == 0) {
    float sn = 0.f, sc = 0.f;
    for (int j = 0; j < 128; ++j) {
      sn += nb2[j] * mw1[j * 128 + t];
      sc += eb2[j] * mw1[(128 + j) * 128 + t];
    }
    bn[t] = sn;
    bc[t] = mb1[t] + sc;
  }
}

// Wave-shuffle scan: 2 barriers instead of 20 (Hillis-Steele over LDS).
__global__ __launch_bounds__(1024) void scan_kernel(const int* __restrict__ hist,
                                                    int* __restrict__ cursor, int G) {
  __shared__ int wsum[16];
  int tid = threadIdx.x;
  int lane = tid & 63, wv = tid >> 6;
  int per = (G + 1023) >> 10;
  int b0 = tid * per;
  bool vec = ((per & 3) == 0) && ((G & 3) == 0) && (b0 + per <= G);
  int sum = 0;
  if (vec) {
    for (int i = 0; i < per; i += 4) {
      int4 h = *(const int4*)&hist[b0 + i];
      sum += h.x + h.y + h.z + h.w;
    }
  } else {
    for (int i = 0; i < per; ++i)
      if (b0 + i < G) sum += hist[b0 + i];
  }
  // inclusive scan within wave
  int inc = sum;
#pragma unroll
  for (int off = 1; off < 64; off <<= 1) {
    int v = __shfl_up(inc, off, 64);
    if (lane >= off) inc += v;
  }
  if (lane == 63) wsum[wv] = inc;
  __syncthreads();
  if (wv == 0) {
    int v = (lane < 16) ? wsum[lane] : 0;
#pragma unroll
    for (int off = 1; off < 16; off <<= 1) {
      int t2 = __shfl_up(v, off, 64);
      if (lane >= off) v += t2;
    }
    if (lane < 16) wsum[lane] = v;
  }
  __syncthreads();
  int wpre = (wv == 0) ? 0 : wsum[wv - 1];
  int run = wpre + inc - sum;   // exclusive prefix for this thread's range
  if (vec) {
    for (int i = 0; i < per; i += 4) {
      int4 h = *(const int4*)&hist[b0 + i];
      int4 c;
      c.x = run;
      c.y = c.x + h.x;
      c.z = c.y + h.y;
      c.w = c.z + h.z;
      *(int4*)&cursor[b0 + i] = c;
      run = c.w + h.w;
    }
  } else {
    for (int i = 0; i < per; ++i)
      if (b0 + i < G) {
        cursor[b0 + i] = run;
        run += hist[b0 + i];
      }
  }
}

// ---------------------------------------------------------------------------
// Merged node + scatter kernel (256 threads):
//   blocks [0,nNode):   node MLP: node_pre = silu(x@nw1+nb1) @ Wn + bn
//   blocks [nNode,..):  scatter (src,tgt) into sorted position, 16 edges/thread
// Plain int2 stores (R11 lesson: nontemporal stores bypass L2 and made
// edge_kernel's st_sorted reads HBM-bound — net loss).
// ---------------------------------------------------------------------------
__global__ __launch_bounds__(256, 3) void scatter_node_kernel(
    const int* __restrict__ eidx, int* __restrict__ cursor,
    int2* __restrict__ st, int E, int nNode,
    const float* __restrict__ x, const float* __restrict__ nb1,
    const unsigned short* __restrict__ nw1t, const unsigned short* __restrict__ wnt,
    const float* __restrict__ bn, unsigned short* __restrict__ node_pre, int N) {
  __shared__ __align__(16) unsigned short s_x[128 * P];
  __shared__ __align__(16) float s_b1[128];
  __shared__ __align__(16) float s_bn[128];

  if (blockIdx.x >= (unsigned)nNode) {
    int e0 = (blockIdx.x - nNode) * 4096 + threadIdx.x * 16;
    if (e0 + 15 < E && (E & 3) == 0) {
      int4 sv[4], tv[4];
#pragma unroll
      for (int g = 0; g < 4; ++g) {
        sv[g] = *(const int4*)&eidx[e0 + g * 4];
        tv[g] = *(const int4*)&eidx[E + e0 + g * 4];
      }
      int pos[16];
#pragma unroll
      for (int g = 0; g < 4; ++g) {
        pos[g * 4 + 0] = atomicAdd(&cursor[tv[g].x], 1);
        pos[g * 4 + 1] = atomicAdd(&cursor[tv[g].y], 1);
        pos[g * 4 + 2] = atomicAdd(&cursor[tv[g].z], 1);
        pos[g * 4 + 3] = atomicAdd(&cursor[tv[g].w], 1);
      }
#pragma unroll
      for (int g = 0; g < 4; ++g) {
        st[pos[g * 4 + 0]] = make_int2(sv[g].x, tv[g].x);
        st[pos[g * 4 + 1]] = make_int2(sv[g].y, tv[g].y);
        st[pos[g * 4 + 2]] = make_int2(sv[g].z, tv[g].z);
        st[pos[g * 4 + 3]] = make_int2(sv[g].w, tv[g].w);
      }
    } else {
#pragma unroll
      for (int k = 0; k < 16; ++k) {
        int e = e0 + k;
        if (e < E) {
          int tg = eidx[E + e];
          int p = atomicAdd(&cursor[tg], 1);
          st[p] = make_int2(eidx[e], tg);
        }
      }
    }
    return;
  }

  int tid = threadIdx.x;
  long base = (long)blockIdx.x * 128;

#pragma unroll
  for (int i = 0; i < 16; ++i) {
    int flat = tid + i * 256;      // 4096 float4 = 128 rows x 32
    int row = flat >> 5;
    int c4 = (flat & 31) << 2;
    float4 v = make_float4(0.f, 0.f, 0.f, 0.f);
    if (base + row < N) v = *(const float4*)&x[(base + row) * 128 + c4];
    uint2 w; w.x = pack2bf(v.x, v.y); w.y = pack2bf(v.z, v.w);
    *(uint2*)&s_x[row * P + c4] = w;
  }
  if (tid < 128) { s_b1[tid] = nb1[tid]; s_bn[tid] = bn[tid]; }
  __syncthreads();

  int wave = tid >> 6, lane = tid & 63;
  int q = lane >> 4, l16 = lane & 15;
  int m0w = wave * 32;

  f32x4 b1_0 = *(const f32x4*)&s_b1[m0w + q * 4];
  f32x4 b1_1 = *(const f32x4*)&s_b1[m0w + 16 + q * 4];

  short8 a1[2][4];
  load_A128(nw1t, m0w, l16, q, a1);
  f32x4 acc[2][8];
  gemm_T_init<8>(a1, s_x, l16, q, acc, b1_0, b1_1);
  __syncthreads();
  epilogue_nb<true, 8>(acc, s_x, m0w, l16, q);
  __syncthreads();

  f32x4 bn_0 = *(const f32x4*)&s_bn[m0w + q * 4];
  f32x4 bn_1 = *(const f32x4*)&s_bn[m0w + 16 + q * 4];
  short8 a2[2][4];
  load_A128(wnt, m0w, l16, q, a2);
  gemm_T_init<8>(a2, s_x, l16, q, acc, bn_0, bn_1);

  // store node_pre[node][feat] packed 8B (bias already folded)
#pragma unroll
  for (int rt = 0; rt < 2; ++rt) {
    int f0 = m0w + rt * 16 + q * 4;
#pragma unroll
    for (int ct = 0; ct < 8; ++ct) {
      long n = base + ct * 16 + l16;
      if (n < N) {
        uint2 w;
        w.x = pack2bf(acc[rt][ct][0], acc[rt][ct][1]);
        w.y = pack2bf(acc[rt][ct][2], acc[rt][ct][3]);
        *(uint2*)&node_pre[n * 128 + f0] = w;
      }
    }
  }
}

// ---------------------------------------------------------------------------
// Edge kernel — R5/R10 structure (proven 124.9-128 us; VALUBusy 71%, occ 41%).
// Thrice-confirmed lesson (R6/R7/R11): this kernel sits EXACTLY at the
// 128-unified-reg / 4-waves-per-SIMD boundary. ANY change that extends a live
// range (bias C-init, paired-row reduction, setprio scheduling) adds ~4 VGPRs,
// drops occupancy to 3 waves/SIMD and costs ~12 us. Do not touch without
// verifying VGPR_Count stays at 64.
// ---------------------------------------------------------------------------
__global__ __launch_bounds__(256, 3) void edge_kernel(
    const int2* __restrict__ st_sorted, const float* __restrict__ node_pos,
    const float* __restrict__ grid_pos, const float* __restrict__ ori,
    const unsigned short* __restrict__ ew1t8, const float* __restrict__ eb1,
    const unsigned short* __restrict__ wct, const float* __restrict__ bc,
    const unsigned short* __restrict__ node_pre, float* __restrict__ sums, int E) {
  __shared__ __align__(16) unsigned short s_h[128 * P];
  __shared__ int s_src[128];
  __shared__ int s_tgt[128];
  __shared__ __align__(16) float s_eb1[128];
  __shared__ __align__(16) float s_bc[128];

  int tid = threadIdx.x;
  int base = blockIdx.x * 128;

  if (tid < 128) {
    s_eb1[tid] = eb1[tid];
    s_bc[tid] = bc[tid];
    int eg = base + tid;
    int s = 0, tg = -1;
    float a0 = 0.f, a1 = 0.f, a2 = 0.f, a3 = 0.f, a4 = 0.f, a5 = 0.f;
    if (eg < E) {
      int2 st = st_sorted[eg];
      s = st.x; tg = st.y;
      // vectorized gathers (dwordx4 needs only dword alignment on CDNA)
      float2 p01 = *(const float2*)&node_pos[s * 3];
      float pz = node_pos[s * 3 + 2];
      float2 g01 = *(const float2*)&grid_pos[tg * 3];
      float gz = grid_pos[tg * 3 + 2];
      float4 o0 = *(const float4*)&ori[(long)s * 9];      // o[0..3]
      float4 o1 = *(const float4*)&ori[(long)s * 9 + 4];  // o[4..7]
      float o8 = ori[(long)s * 9 + 8];
      float rx = g01.x - p01.x, ry = g01.y - p01.y, rz = gz - pz;
      a0 = p01.x; a1 = p01.y; a2 = pz;
      a3 = rx * o0.x + ry * o0.w + rz * o1.z;   // o0,o3,o6
      a4 = rx * o0.y + ry * o1.x + rz * o1.w;   // o1,o4,o7
      a5 = rx * o0.z + ry * o1.y + rz * o8;     // o2,o5,o8
    }
    s_src[tid] = s;
    s_tgt[tid] = tg;
    uint4 w0;
    w0.x = pack2bf(a0, a1); w0.y = pack2bf(a2, a3); w0.z = pack2bf(a4, a5); w0.w = 0u;
    *(uint4*)&s_h[tid * P] = w0;   // attr row [edge][k0..7]
  }

  int wave = tid >> 6, lane = tid & 63;
  int q = lane >> 4, l16 = lane & 15;
  int m0w = wave * 32;
  short8 z8 = (short8){0, 0, 0, 0, 0, 0, 0, 0};
  const f32x4 Z = (f32x4){0.f, 0.f, 0.f, 0.f};

  // ew1^T rows (K=8) -> registers, q==0 lanes only (issued pre-barrier,
  // overlaps the geometry phase; L2-resident)
  short8 ae0 = z8, ae1 = z8;
  if (q == 0) {
    ae0 = *(const short8*)&ew1t8[(m0w + l16) * 8];
    ae1 = *(const short8*)&ew1t8[(m0w + 16 + l16) * 8];
  }

  __syncthreads();

  // --- node_pre prefetch: issue NOW, consume after the h1 epilogue. ---
  // All 64 lanes: lane (q,l16) of tile ct loads feats [m0w+q*8, m0w+q*8+8)
  // of row src[ct*16+l16] -> B[k=q*8+j][n=l16] with k spanning both rt tiles.
  short8 pre[8];
#pragma unroll
  for (int ct = 0; ct < 8; ++ct) {
    long srow = (long)s_src[ct * 16 + l16] * 128;
    pre[ct] = *(const short8*)&node_pre[srow + m0w + q * 8];
  }

  // GEMM0: D[h][edge] = ew1^T · attr^T (single K-tile, direct-init C=0)
  f32x4 acc[2][8];
#pragma unroll
  for (int ct = 0; ct < 8; ++ct) {
    short8 b = z8;
    if (q == 0) b = *(const short8*)&s_h[(ct * 16 + l16) * P];
    acc[0][ct] = __builtin_amdgcn_mfma_f32_16x16x32_bf16(ae0, b, Z, 0, 0, 0);
    acc[1][ct] = __builtin_amdgcn_mfma_f32_16x16x32_bf16(ae1, b, Z, 0, 0, 0);
  }
  __syncthreads();  // attr reads done before overwrite

  epilogue_T<true, 8>(acc, s_eb1, s_h, m0w, l16, q);   // h1 -> s_h[edge][feat]

  // Wc^T rows for this wave -> registers (L2-resident). Loaded here (not
  // earlier) so they don't add to VGPR pressure while acc is live for GEMM0.
  short8 awc[2][4];
  load_A128(wct, m0w, l16, q, awc);

  __syncthreads();

  // acc := node_pre[src[edge]][feat] from the prefetched fragments.
  // rt=0: A[i][k]=delta(k,i); rt=1: A[i][k]=delta(k,i+16).
  short8 aI_lo, aI_hi;
#pragma unroll
  for (int j = 0; j < 8; ++j) {
    aI_lo[j] = ((q * 8 + j) == l16) ? (short)0x3F80 : (short)0;
    aI_hi[j] = ((q * 8 + j) == (l16 + 16)) ? (short)0x3F80 : (short)0;
  }
#pragma unroll
  for (int ct = 0; ct < 8; ++ct) {
    acc[0][ct] = __builtin_amdgcn_mfma_f32_16x16x32_bf16(aI_lo, pre[ct], Z, 0, 0, 0);
    acc[1][ct] = __builtin_amdgcn_mfma_f32_16x16x32_bf16(aI_hi, pre[ct], Z, 0, 0, 0);
  }

  // GEMM1: acc += Wc^T · h1^T
  gemm_T_acc<8>(awc, s_h, l16, q, acc);
  __syncthreads();  // h1 reads done

  epilogue_T<true, 8>(acc, s_bc, s_h, m0w, l16, q);    // h2 -> s_h[edge][feat]
  __syncthreads();

  // segmented reduction: thread = (colpair, 32-row chunk); flush per run.
  {
    int cp = tid & 63;
    int chunk = tid >> 6;       // 4 chunks x 32 rows
    int c0 = cp * 2;
    int row0 = chunk * 32;
    float v0 = 0.f, v1 = 0.f;
    int cur = s_tgt[row0];
    for (int r = 0; r < 32; ++r) {
      int row = row0 + r;
      int tg = s_tgt[row];
      if (tg != cur) {
        if (cur >= 0) {
          atomicAdd(&sums[(long)cur * 128 + c0], v0);
          atomicAdd(&sums[(long)cur * 128 + c0 + 1], v1);
        }
        v0 = 0.f; v1 = 0.f; cur = tg;
      }
      unsigned w = *(const unsigned*)&s_h[row * P + c0];
      v0 += bf2f((unsigned short)w);
      v1 += bf2f((unsigned short)(w >> 16));
    }
    if (cur >= 0) {
      atomicAdd(&sums[(long)cur * 128 + c0], v0);
      atomicAdd(&sums[(long)cur * 128 + c0 + 1], v1);
    }
  }
}

// ---------------------------------------------------------------------------
// Grid kernel (transposed): x = sums/clip(hist,1); y = x@mw2+mb2;
// out = silu(y@uw1+ub1)@uw2 + ub2.  Final store: packed float4.
// Tile = 32 grid rows (2 ct tiles) -> 1024 blocks = 4 blocks/CU. LDS ~19 KB.
// Bias folded into MFMA C-init throughout.
// ---------------------------------------------------------------------------
__global__ __launch_bounds__(256, 3) void grid_kernel(
    const float* __restrict__ sums, const int* __restrict__ hist,
    const float* __restrict__ mb2, const float* __restrict__ ub1,
    const float* __restrict__ ub2, const unsigned short* __restrict__ mw2t,
    const unsigned short* __restrict__ uw1t, const unsigned short* __restrict__ uw2t,
    float* __restrict__ out, int G) {
  __shared__ __align__(16) unsigned short s_x[32 * P];
  __shared__ __align__(16) float s_bm[128];
  __shared__ __align__(16) float s_b1[128];
  __shared__ __align__(16) float s_b2[128];
  int tid = threadIdx.x;
  long base = (long)blockIdx.x * 32;

#pragma unroll
  for (int i = 0; i < 4; ++i) {
    int flat = tid + i * 256;       // 1024 float4 = 32 rows x 32
    int row = flat >> 5;
    int c4 = (flat & 31) << 2;
    float4 v = make_float4(0.f, 0.f, 0.f, 0.f);
    float inv = 1.f;
    if (base + row < G) {
      v = *(const float4*)&sums[(base + row) * 128 + c4];
      int c = hist[base + row];
      inv = __builtin_amdgcn_rcpf((float)(c < 1 ? 1 : c));
    }
    uint2 w; w.x = pack2bf(v.x * inv, v.y * inv); w.y = pack2bf(v.z * inv, v.w * inv);
    *(uint2*)&s_x[row * P + c4] = w;
  }
  if (tid < 128) { s_bm[tid] = mb2[tid]; s_b1[tid] = ub1[tid]; s_b2[tid] = ub2[tid]; }
  __syncthreads();

  int wave = tid >> 6, lane = tid & 63;
  int q = lane >> 4, l16 = lane & 15;
  int m0w = wave * 32;

  f32x4 acc[2][2];
  short8 aw[2][4];

  f32x4 bm0 = *(const f32x4*)&s_bm[m0w + q * 4];
  f32x4 bm1 = *(const f32x4*)&s_bm[m0w + 16 + q * 4];
  f32x4 b10 = *(const f32x4*)&s_b1[m0w + q * 4];
  f32x4 b11 = *(const f32x4*)&s_b1[m0w + 16 + q * 4];
  f32x4 b20 = *(const f32x4*)&s_b2[m0w + q * 4];
  f32x4 b21 = *(const f32x4*)&s_b2[m0w + 16 + q * 4];

  // GEMM A: grid_feat = x@mw2 + mb2 (no activation)
  load_A128(mw2t, m0w, l16, q, aw);
  gemm_T_init<2>(aw, s_x, l16, q, acc, bm0, bm1);
  __syncthreads();
  epilogue_nb<false, 2>(acc, s_x, m0w, l16, q);
  __syncthreads();

  // GEMM B: silu(y@uw1 + ub1)
  load_A128(uw1t, m0w, l16, q, aw);
  gemm_T_init<2>(aw, s_x, l16, q, acc, b10, b11);
  __syncthreads();
  epilogue_nb<true, 2>(acc, s_x, m0w, l16, q);
  __syncthreads();

  // GEMM C: out = h@uw2 + ub2  (fp32 float4 stores, bias folded)
  load_A128(uw2t, m0w, l16, q, aw);
  gemm_T_init<2>(aw, s_x, l16, q, acc, b20, b21);

#pragma unroll
  for (int rt = 0; rt < 2; ++rt) {
    int f0 = m0w + rt * 16 + q * 4;
#pragma unroll
    for (int ct = 0; ct < 2; ++ct) {
      long g = base + ct * 16 + l16;
      if (g < G) {
        float4 o = make_float4(acc[rt][ct][0], acc[rt][ct][1],
                               acc[rt][ct][2], acc[rt][ct][3]);
        *(float4*)&out[g * 128 + f0] = o;
      }
    }
  }
}

extern "C" void kernel_launch(void* const* d_in, const int* in_sizes, int n_in,
                              void* d_out, int out_size, void* d_ws, size_t ws_size,
                              hipStream_t stream) {
  const float* x    = (const float*)d_in[0];
  const float* npos = (const float*)d_in[1];
  const float* gpos = (const float*)d_in[2];
  const int*   eidx = (const int*)d_in[3];
  const float* ori  = (const float*)d_in[4];
  const float* nw1 = (const float*)d_in[5];
  const float* nb1 = (const float*)d_in[6];
  const float* nw2 = (const float*)d_in[7];
  const float* nb2 = (const float*)d_in[8];
  const float* ew1 = (const float*)d_in[9];
  const float* eb1 = (const float*)d_in[10];
  const float* ew2 = (const float*)d_in[11];
  const float* eb2 = (const float*)d_in[12];
  const float* mw1 = (const float*)d_in[13];
  const float* mb1 = (const float*)d_in[14];
  const float* mw2 = (const float*)d_in[15];
  const float* mb2 = (const float*)d_in[16];
  const float* uw1 = (const float*)d_in[17];
  const float* ub1 = (const float*)d_in[18];
  const float* uw2 = (const float*)d_in[19];
  const float* ub2 = (const float*)d_in[20];

  int N = in_sizes[0] / 128;
  int G = in_sizes[2] / 3;
  int E = in_sizes[3] / 2;

  // ws layout within R1's proven footprint (~43 MB). Sorted-edge buffer
  // (E*8 = 8 MB) lives in d_out (16.8 MB) — dead until grid_kernel (last
  // launch); stream order makes the reuse safe.
  char* ws = (char*)d_ws;
  size_t off = 0;
  float* sums = (float*)(ws + off);            off += (size_t)G * 128 * 4;
  int* hist = (int*)(ws + off);                off += (size_t)G * 4;
  int* cursor = (int*)(ws + off);              off += (size_t)G * 4;
  unsigned short* node_pre = (unsigned short*)(ws + off); off += (size_t)N * 128 * 2;
  off = (off + 255) & ~(size_t)255;
  unsigned short* w_nw1t = (unsigned short*)(ws + off); off += 128 * 128 * 2;
  unsigned short* w_wnt  = (unsigned short*)(ws + off); off += 128 * 128 * 2;
  unsigned short* w_wct  = (unsigned short*)(ws + off); off += 128 * 128 * 2;
  unsigned short* w_mw2t = (unsigned short*)(ws + off); off += 128 * 128 * 2;
  unsigned short* w_uw1t = (unsigned short*)(ws + off); off += 128 * 128 * 2;
  unsigned short* w_uw2t = (unsigned short*)(ws + off); off += 128 * 128 * 2;
  unsigned short* w_ew1t8 = (unsigned short*)(ws + off); off += 128 * 8 * 2;
  float* bn = (float*)(ws + off); off += 128 * 4;
  float* bc = (float*)(ws + off); off += 128 * 4;

  int2* st_sorted = (int2*)d_out;   // scratch until grid_kernel overwrites it

  int nScat = (E + 4095) / 4096;    // 16 edges/thread
  int nNode = (N + 127) / 128;
  int nHist = (E + 4095) / 4096;    // 16 edges/thread

  // zero sums + hist (contiguous)
  hipMemsetAsync(sums, 0, ((size_t)G * 128 + G) * 4, stream);

  fold_hist_kernel<<<64 + nHist, 256, 0, stream>>>(
      nw1, nw2, nb2, ew2, eb2, mw1, mb1, mw2, uw1, uw2, ew1,
      w_nw1t, w_wnt, w_wct, w_mw2t, w_uw1t, w_uw2t, w_ew1t8, bn, bc,
      eidx, hist, E);
  scan_kernel<<<1, 1024, 0, stream>>>(hist, cursor, G);
  scatter_node_kernel<<<nNode + nScat, 256, 0, stream>>>(
      eidx, cursor, st_sorted, E, nNode,
      x, nb1, w_nw1t, w_wnt, bn, node_pre, N);
  edge_kernel<<<(E + 127) / 128, 256, 0, stream>>>(st_sorted, npos, gpos, ori,
                                                   w_ew1t8, eb1, w_wct, bc,
                                                   node_pre, sums, E);
  grid_kernel<<<(G + 31) / 32, 256, 0, stream>>>(sums, hist, mb2, ub1, ub2,
                                                 w_mw2t, w_uw1t, w_uw2t,
                                                 (float*)d_out, G);
}